// Round 4
// baseline (1178.153 us; speedup 1.0000x reference)
//
#include <hip/hip_runtime.h>

#define N_NODES 50000
#define N_EDGES 1600000
#define IN_CH   256
#define ADP     64
#define EDGE_DIM 32
#define NB_SCAN 196   // ceil(50000/256)

// ---------------- K0: degree histogram over src nodes ------------------------
__global__ __launch_bounds__(256) void k_hist(const int* __restrict__ ei_src,
                                              int* __restrict__ deg) {
    int i = blockIdx.x * 256 + threadIdx.x;
    if (i < N_EDGES) atomicAdd(&deg[ei_src[i]], 1);
}

// ---------------- K1a: per-block degree sums ---------------------------------
__global__ __launch_bounds__(256) void k_bsum(const int* __restrict__ deg,
                                              int* __restrict__ bsum) {
    __shared__ int wsum[4];
    int idx = blockIdx.x * 256 + threadIdx.x;
    int v = (idx < N_NODES) ? deg[idx] : 0;
    for (int o = 32; o > 0; o >>= 1) v += __shfl_down(v, o, 64);
    if ((threadIdx.x & 63) == 0) wsum[threadIdx.x >> 6] = v;
    __syncthreads();
    if (threadIdx.x == 0) bsum[blockIdx.x] = wsum[0] + wsum[1] + wsum[2] + wsum[3];
}

// ---------------- K1b: scan the 196 block sums (1 block) ---------------------
__global__ __launch_bounds__(256) void k_bscan(const int* __restrict__ bsum,
                                               int* __restrict__ bpre) {
    __shared__ int a[256], b[256];
    int t = threadIdx.x;
    int v = (t < NB_SCAN) ? bsum[t] : 0;
    a[t] = v; __syncthreads();
    int* src = a; int* dst = b;
    for (int o = 1; o < 256; o <<= 1) {
        int x = src[t]; if (t >= o) x += src[t - o];
        dst[t] = x; __syncthreads();
        int* tmp = src; src = dst; dst = tmp;
    }
    if (t < NB_SCAN) bpre[t] = src[t] - v;
}

// ---------------- K1c: per-node exclusive offsets ----------------------------
__global__ __launch_bounds__(256) void k_offs(const int* __restrict__ deg,
                                              const int* __restrict__ bpre,
                                              int* __restrict__ offs,
                                              int* __restrict__ cursor) {
    __shared__ int a[256], b[256];
    int t = threadIdx.x;
    int idx = blockIdx.x * 256 + t;
    int v = (idx < N_NODES) ? deg[idx] : 0;
    a[t] = v; __syncthreads();
    int* src = a; int* dst = b;
    for (int o = 1; o < 256; o <<= 1) {
        int x = src[t]; if (t >= o) x += src[t - o];
        dst[t] = x; __syncthreads();
        int* tmp = src; src = dst; dst = tmp;
    }
    if (idx < N_NODES) {
        int e = bpre[blockIdx.x] + src[t] - v;
        offs[idx] = e; cursor[idx] = e;
    }
}

// ---------------- K2: bucket edge ids by src ---------------------------------
__global__ __launch_bounds__(256) void k_scatter(const int* __restrict__ ei_src,
                                                 int* __restrict__ cursor,
                                                 int* __restrict__ elist) {
    int i = blockIdx.x * 256 + threadIdx.x;
    if (i < N_EDGES) {
        int s = ei_src[i];
        elist[atomicAdd(&cursor[s], 1)] = i;
    }
}

// ---------------- K3: gather + time-proj + mean ------------------------------
// One wave per node. Register-prefetch chunk c+1's 8 edge rows (coalesced
// 64-lane float4 gather) while computing chunk c from LDS; ds_write after
// compute. Fixed 8-edge unrolled inner with multiply-mask tail.
__global__ __launch_bounds__(256) void k_gatherproj(const float* __restrict__ ea,
                                                    const int* __restrict__ offs,
                                                    const int* __restrict__ deg,
                                                    const int* __restrict__ elist,
                                                    const float* __restrict__ Wt,
                                                    const float* __restrict__ bt,
                                                    float* __restrict__ ntf) {
    __shared__ float4 buf[4][2][8][8];   // [wave][db][edge][seg] = 8KB
    int t = threadIdx.x;
    int lane = t & 63, wv = t >> 6;
    float w[EDGE_DIM];
    {
        const float4* w4 = (const float4*)(Wt + (size_t)lane * EDGE_DIM);
        #pragma unroll
        for (int k4 = 0; k4 < 8; k4++) {
            float4 v = w4[k4];
            w[4*k4+0] = v.x; w[4*k4+1] = v.y; w[4*k4+2] = v.z; w[4*k4+3] = v.w;
        }
    }
    float bias = bt[lane];
    int n = blockIdx.x * 4 + wv;
    if (n >= N_NODES) return;
    int st = offs[n], d = deg[n];
    int sub = lane >> 3;   // edge slot 0..7
    int seg = lane & 7;    // float4 within row
    const float4* ea4 = (const float4*)ea;
    float acc = 0.f;
    int nch = (d + 7) >> 3;
    if (d > 0) {
        int e0 = elist[st + min(sub, d - 1)];
        buf[wv][0][sub][seg] = ea4[(size_t)e0 * 8 + seg];
    }
    for (int c = 0; c < nch; c++) {
        int cur = c & 1;
        float4 pf;
        bool hasnext = (c + 1 < nch);
        if (hasnext) {
            int idx = st + (c + 1) * 8 + sub;
            int e = elist[min(idx, st + d - 1)];
            pf = ea4[(size_t)e * 8 + seg];          // global -> reg (overlaps)
        }
        int rem = d - c * 8;
        const float4* bb = &buf[wv][cur][0][0];
        #pragma unroll
        for (int j = 0; j < 8; j++) {
            float s0 = bias, s1 = 0.f;
            #pragma unroll
            for (int k4 = 0; k4 < 8; k4 += 2) {
                float4 v0 = bb[j * 8 + k4];
                float4 v1 = bb[j * 8 + k4 + 1];
                s0 += v0.x*w[4*k4+0] + v0.y*w[4*k4+1] + v0.z*w[4*k4+2] + v0.w*w[4*k4+3];
                s1 += v1.x*w[4*k4+4] + v1.y*w[4*k4+5] + v1.z*w[4*k4+6] + v1.w*w[4*k4+7];
            }
            float m = (j < rem) ? 1.f : 0.f;
            acc += m * fmaxf(s0 + s1, 0.f);
        }
        if (hasnext) buf[wv][cur ^ 1][sub][seg] = pf;
    }
    ntf[(size_t)n * ADP + lane] = acc / fmaxf((float)d, 1.f);
}

// ---------------- K4: node_feat = relu(x @ W_down^T + b_down) ----------------
// W in LDS at lds[k*65+c]: pad-65 => conflict-free reads (fixed k, lanes c)
// AND conflict-free writes (fixed c, k varies). 8-node register blocking:
// 8 FMA per LDS read.
__global__ __launch_bounds__(256) void k_down(const float* __restrict__ x,
                                              const float* __restrict__ Wd,
                                              const float* __restrict__ bd,
                                              float* __restrict__ nfeat) {
    __shared__ float lds[IN_CH * 65];   // 66.6KB
    for (int idx = threadIdx.x; idx < IN_CH * ADP; idx += 256) {
        int c = idx >> 8;
        int k = idx & 255;
        lds[k * 65 + c] = Wd[idx];
    }
    __syncthreads();
    int wv = threadIdx.x >> 6;
    int lane = threadIdx.x & 63;
    float b = bd[lane];
    int g = blockIdx.x * 4 + wv;
    if (g >= N_NODES / 8) return;      // 6250 groups
    int n0 = g * 8;
    const float4* r0 = (const float4*)(x + (size_t)(n0 + 0) * IN_CH);
    const float4* r1 = (const float4*)(x + (size_t)(n0 + 1) * IN_CH);
    const float4* r2 = (const float4*)(x + (size_t)(n0 + 2) * IN_CH);
    const float4* r3 = (const float4*)(x + (size_t)(n0 + 3) * IN_CH);
    const float4* r4 = (const float4*)(x + (size_t)(n0 + 4) * IN_CH);
    const float4* r5 = (const float4*)(x + (size_t)(n0 + 5) * IN_CH);
    const float4* r6 = (const float4*)(x + (size_t)(n0 + 6) * IN_CH);
    const float4* r7 = (const float4*)(x + (size_t)(n0 + 7) * IN_CH);
    float a0 = b, a1 = b, a2 = b, a3 = b, a4 = b, a5 = b, a6 = b, a7 = b;
    #pragma unroll 2
    for (int k4 = 0; k4 < IN_CH / 4; k4++) {
        float4 v0 = r0[k4], v1 = r1[k4], v2 = r2[k4], v3 = r3[k4];
        float4 v4 = r4[k4], v5 = r5[k4], v6 = r6[k4], v7 = r7[k4];
        const float* p0 = (const float*)&v0;
        const float* p1 = (const float*)&v1;
        const float* p2 = (const float*)&v2;
        const float* p3 = (const float*)&v3;
        const float* p4 = (const float*)&v4;
        const float* p5 = (const float*)&v5;
        const float* p6 = (const float*)&v6;
        const float* p7 = (const float*)&v7;
        #pragma unroll
        for (int j = 0; j < 4; j++) {
            float wt = lds[(4 * k4 + j) * 65 + lane];
            a0 += p0[j] * wt; a1 += p1[j] * wt; a2 += p2[j] * wt; a3 += p3[j] * wt;
            a4 += p4[j] * wt; a5 += p5[j] * wt; a6 += p6[j] * wt; a7 += p7[j] * wt;
        }
    }
    nfeat[(size_t)(n0 + 0) * ADP + lane] = fmaxf(a0, 0.f);
    nfeat[(size_t)(n0 + 1) * ADP + lane] = fmaxf(a1, 0.f);
    nfeat[(size_t)(n0 + 2) * ADP + lane] = fmaxf(a2, 0.f);
    nfeat[(size_t)(n0 + 3) * ADP + lane] = fmaxf(a3, 0.f);
    nfeat[(size_t)(n0 + 4) * ADP + lane] = fmaxf(a4, 0.f);
    nfeat[(size_t)(n0 + 5) * ADP + lane] = fmaxf(a5, 0.f);
    nfeat[(size_t)(n0 + 6) * ADP + lane] = fmaxf(a6, 0.f);
    nfeat[(size_t)(n0 + 7) * ADP + lane] = fmaxf(a7, 0.f);
}

// ---------------- K5: fused = relu(W_fusion @ [nf | ntf] + b) ----------------
__global__ __launch_bounds__(256) void k_fuse(const float* __restrict__ nfeat,
                                              const float* __restrict__ ntf,
                                              const float* __restrict__ Wf,
                                              const float* __restrict__ bf,
                                              float* __restrict__ fused) {
    __shared__ float lds[2 * ADP * 65];  // 33.3KB
    for (int idx = threadIdx.x; idx < 2 * ADP * ADP; idx += 256) {
        int c = idx >> 7;
        int k = idx & 127;
        lds[k * 65 + c] = Wf[idx];
    }
    __syncthreads();
    int wv = threadIdx.x >> 6;
    int lane = threadIdx.x & 63;
    float b = bf[lane];
    int g = blockIdx.x * 4 + wv;
    if (g >= N_NODES / 8) return;
    int n0 = g * 8;
    float a0 = b, a1 = b, a2 = b, a3 = b, a4 = b, a5 = b, a6 = b, a7 = b;
    #pragma unroll
    for (int half = 0; half < 2; half++) {
        const float* srcbase = half ? ntf : nfeat;
        const float4* r0 = (const float4*)(srcbase + (size_t)(n0 + 0) * ADP);
        const float4* r1 = (const float4*)(srcbase + (size_t)(n0 + 1) * ADP);
        const float4* r2 = (const float4*)(srcbase + (size_t)(n0 + 2) * ADP);
        const float4* r3 = (const float4*)(srcbase + (size_t)(n0 + 3) * ADP);
        const float4* r4 = (const float4*)(srcbase + (size_t)(n0 + 4) * ADP);
        const float4* r5 = (const float4*)(srcbase + (size_t)(n0 + 5) * ADP);
        const float4* r6 = (const float4*)(srcbase + (size_t)(n0 + 6) * ADP);
        const float4* r7 = (const float4*)(srcbase + (size_t)(n0 + 7) * ADP);
        #pragma unroll 2
        for (int k4 = 0; k4 < ADP / 4; k4++) {
            float4 v0 = r0[k4], v1 = r1[k4], v2 = r2[k4], v3 = r3[k4];
            float4 v4 = r4[k4], v5 = r5[k4], v6 = r6[k4], v7 = r7[k4];
            const float* p0 = (const float*)&v0;
            const float* p1 = (const float*)&v1;
            const float* p2 = (const float*)&v2;
            const float* p3 = (const float*)&v3;
            const float* p4 = (const float*)&v4;
            const float* p5 = (const float*)&v5;
            const float* p6 = (const float*)&v6;
            const float* p7 = (const float*)&v7;
            #pragma unroll
            for (int j = 0; j < 4; j++) {
                float wt = lds[(half * ADP + 4 * k4 + j) * 65 + lane];
                a0 += p0[j] * wt; a1 += p1[j] * wt; a2 += p2[j] * wt; a3 += p3[j] * wt;
                a4 += p4[j] * wt; a5 += p5[j] * wt; a6 += p6[j] * wt; a7 += p7[j] * wt;
            }
        }
    }
    fused[(size_t)(n0 + 0) * ADP + lane] = fmaxf(a0, 0.f);
    fused[(size_t)(n0 + 1) * ADP + lane] = fmaxf(a1, 0.f);
    fused[(size_t)(n0 + 2) * ADP + lane] = fmaxf(a2, 0.f);
    fused[(size_t)(n0 + 3) * ADP + lane] = fmaxf(a3, 0.f);
    fused[(size_t)(n0 + 4) * ADP + lane] = fmaxf(a4, 0.f);
    fused[(size_t)(n0 + 5) * ADP + lane] = fmaxf(a5, 0.f);
    fused[(size_t)(n0 + 6) * ADP + lane] = fmaxf(a6, 0.f);
    fused[(size_t)(n0 + 7) * ADP + lane] = fmaxf(a7, 0.f);
}

// ---------------- K6: out = x + fused @ W_up^T + b_up ------------------------
__global__ __launch_bounds__(256) void k_up(const float* __restrict__ fused,
                                            const float* __restrict__ x,
                                            const float* __restrict__ Wu,
                                            const float* __restrict__ bu,
                                            float* __restrict__ out) {
    int t = threadIdx.x;
    float w[ADP];
    {
        const float4* w4 = (const float4*)(Wu + (size_t)t * ADP);
        #pragma unroll
        for (int k4 = 0; k4 < ADP / 4; k4++) {
            float4 v = w4[k4];
            w[4*k4+0] = v.x; w[4*k4+1] = v.y; w[4*k4+2] = v.z; w[4*k4+3] = v.w;
        }
    }
    float b = bu[t];
    for (int n = blockIdx.x * 2; n < N_NODES; n += gridDim.x * 2) {
        const float4* f0 = (const float4*)(fused + (size_t)n * ADP);
        const float4* f1 = (const float4*)(fused + (size_t)(n + 1) * ADP);
        float acc0 = b, acc1 = b;
        #pragma unroll
        for (int k4 = 0; k4 < ADP / 4; k4++) {
            float4 v0 = f0[k4], v1 = f1[k4];
            acc0 += v0.x*w[4*k4+0] + v0.y*w[4*k4+1] + v0.z*w[4*k4+2] + v0.w*w[4*k4+3];
            acc1 += v1.x*w[4*k4+0] + v1.y*w[4*k4+1] + v1.z*w[4*k4+2] + v1.w*w[4*k4+3];
        }
        size_t o0 = (size_t)n * IN_CH + t;
        size_t o1 = (size_t)(n + 1) * IN_CH + t;
        out[o0] = x[o0] + acc0;
        out[o1] = x[o1] + acc1;
    }
}

extern "C" void kernel_launch(void* const* d_in, const int* in_sizes, int n_in,
                              void* d_out, int out_size, void* d_ws, size_t ws_size,
                              hipStream_t stream) {
    const float* x   = (const float*)d_in[0];
    const int*   ei  = (const int*)d_in[1];     // [2, E]; row 0 = src
    const float* ea  = (const float*)d_in[2];
    const float* Wd  = (const float*)d_in[3];
    const float* bd  = (const float*)d_in[4];
    const float* Wt  = (const float*)d_in[5];
    const float* bt  = (const float*)d_in[6];
    const float* Wf  = (const float*)d_in[7];
    const float* bf  = (const float*)d_in[8];
    const float* Wu  = (const float*)d_in[9];
    const float* bu  = (const float*)d_in[10];
    float* out = (float*)d_out;

    int* deg    = (int*)d_ws;                       // [N]
    int* offs   = deg + N_NODES;                    // [N]
    int* cursor = offs + N_NODES;                   // [N]
    int* bsum   = cursor + N_NODES;                 // [256]
    int* bpre   = bsum + 256;                       // [256]
    int* elist  = bpre + 256;                       // [E]
    float* ntf   = (float*)(elist + N_EDGES);       // [N*64]
    float* nfeat = ntf + (size_t)N_NODES * ADP;     // [N*64]
    float* fused = nfeat + (size_t)N_NODES * ADP;   // [N*64]

    hipMemsetAsync(deg, 0, N_NODES * sizeof(int), stream);

    k_hist      <<< 6250, 256, 0, stream>>>(ei, deg);
    k_bsum      <<<NB_SCAN, 256, 0, stream>>>(deg, bsum);
    k_bscan     <<<    1, 256, 0, stream>>>(bsum, bpre);
    k_offs      <<<NB_SCAN, 256, 0, stream>>>(deg, bpre, offs, cursor);
    k_scatter   <<< 6250, 256, 0, stream>>>(ei, cursor, elist);
    k_gatherproj<<<12500, 256, 0, stream>>>(ea, offs, deg, elist, Wt, bt, ntf);
    k_down      <<< 1563, 256, 0, stream>>>(x, Wd, bd, nfeat);
    k_fuse      <<< 1563, 256, 0, stream>>>(nfeat, ntf, Wf, bf, fused);
    k_up        <<< 4096, 256, 0, stream>>>(fused, x, Wu, bu, out);
}

// Round 6
// 827.710 us; speedup vs baseline: 1.4234x; 1.4234x over previous
//
#include <hip/hip_runtime.h>

#define N_NODES 50000
#define N_EDGES 1600000
#define IN_CH   256
#define ADP     64
#define EDGE_DIM 32
#define NB_SCAN 196   // ceil(50000/256)

typedef __fp16 h2 __attribute__((ext_vector_type(2)));
union UH { unsigned int u; h2 h; };

// ---------------- K0: degree histogram over src nodes ------------------------
__global__ __launch_bounds__(256) void k_hist(const int* __restrict__ ei_src,
                                              int* __restrict__ deg) {
    int i = blockIdx.x * 256 + threadIdx.x;
    if (i < N_EDGES) atomicAdd(&deg[ei_src[i]], 1);
}

// ---------------- K1a: per-block degree sums ---------------------------------
__global__ __launch_bounds__(256) void k_bsum(const int* __restrict__ deg,
                                              int* __restrict__ bsum) {
    __shared__ int wsum[4];
    int idx = blockIdx.x * 256 + threadIdx.x;
    int v = (idx < N_NODES) ? deg[idx] : 0;
    for (int o = 32; o > 0; o >>= 1) v += __shfl_down(v, o, 64);
    if ((threadIdx.x & 63) == 0) wsum[threadIdx.x >> 6] = v;
    __syncthreads();
    if (threadIdx.x == 0) bsum[blockIdx.x] = wsum[0] + wsum[1] + wsum[2] + wsum[3];
}

// ---------------- K1b: scan the 196 block sums (1 block) ---------------------
__global__ __launch_bounds__(256) void k_bscan(const int* __restrict__ bsum,
                                               int* __restrict__ bpre) {
    __shared__ int a[256], b[256];
    int t = threadIdx.x;
    int v = (t < NB_SCAN) ? bsum[t] : 0;
    a[t] = v; __syncthreads();
    int* src = a; int* dst = b;
    for (int o = 1; o < 256; o <<= 1) {
        int x = src[t]; if (t >= o) x += src[t - o];
        dst[t] = x; __syncthreads();
        int* tmp = src; src = dst; dst = tmp;
    }
    if (t < NB_SCAN) bpre[t] = src[t] - v;
}

// ---------------- K1c: per-node exclusive offsets ----------------------------
__global__ __launch_bounds__(256) void k_offs(const int* __restrict__ deg,
                                              const int* __restrict__ bpre,
                                              int* __restrict__ offs,
                                              int* __restrict__ cursor) {
    __shared__ int a[256], b[256];
    int t = threadIdx.x;
    int idx = blockIdx.x * 256 + t;
    int v = (idx < N_NODES) ? deg[idx] : 0;
    a[t] = v; __syncthreads();
    int* src = a; int* dst = b;
    for (int o = 1; o < 256; o <<= 1) {
        int x = src[t]; if (t >= o) x += src[t - o];
        dst[t] = x; __syncthreads();
        int* tmp = src; src = dst; dst = tmp;
    }
    if (idx < N_NODES) {
        int e = bpre[blockIdx.x] + src[t] - v;
        offs[idx] = e; cursor[idx] = e;
    }
}

// ---------------- K2: bucket edge ids by src ---------------------------------
__global__ __launch_bounds__(256) void k_scatter(const int* __restrict__ ei_src,
                                                 int* __restrict__ cursor,
                                                 int* __restrict__ elist) {
    int i = blockIdx.x * 256 + threadIdx.x;
    if (i < N_EDGES) {
        int s = ei_src[i];
        elist[atomicAdd(&cursor[s], 1)] = i;
    }
}

// ---------------- K3: gather + time-proj (f16 dot2) + mean -------------------
// One wave per node. Stage 8 edges/chunk: coalesced float4 gather -> cvt to
// f16 -> 8B LDS write per lane (row = 64B). Per edge: 4 ds_read_b128 +
// 16 v_dot2_f32_f16 (4 chains). Halves R3's LDS-pipe cost.
__global__ __launch_bounds__(256) void k_gatherproj(const float* __restrict__ ea,
                                                    const int* __restrict__ offs,
                                                    const int* __restrict__ deg,
                                                    const int* __restrict__ elist,
                                                    const float* __restrict__ Wt,
                                                    const float* __restrict__ bt,
                                                    float* __restrict__ ntf) {
    __shared__ unsigned long long buf[4][8][8];   // [wave][edge][8B seg] = 2KB
    int t = threadIdx.x;
    int lane = t & 63, wv = t >> 6;
    h2 wh[16];
    {
        const float4* w4 = (const float4*)(Wt + (size_t)lane * EDGE_DIM);
        #pragma unroll
        for (int k4 = 0; k4 < 8; k4++) {
            float4 v = w4[k4];
            wh[2 * k4 + 0] = __builtin_amdgcn_cvt_pkrtz(v.x, v.y);
            wh[2 * k4 + 1] = __builtin_amdgcn_cvt_pkrtz(v.z, v.w);
        }
    }
    float bias = bt[lane];
    int n = blockIdx.x * 4 + wv;
    if (n >= N_NODES) return;
    int st = offs[n], d = deg[n];
    int sub = lane >> 3;   // edge slot 0..7
    int seg = lane & 7;    // 16B (4-float) segment within row
    const float4* ea4 = (const float4*)ea;
    float acc = 0.f;
    for (int base = 0; base < d; base += 8) {
        int cnt = min(8, d - base);
        int e = elist[st + base + min(sub, cnt - 1)];
        float4 v = ea4[(size_t)e * 8 + seg];
        UH lo, hi;
        lo.h = __builtin_amdgcn_cvt_pkrtz(v.x, v.y);
        hi.h = __builtin_amdgcn_cvt_pkrtz(v.z, v.w);
        buf[wv][sub][seg] = ((unsigned long long)hi.u << 32) | lo.u;
        const uint4* bb = (const uint4*)&buf[wv][0][0];
        #pragma unroll 1
        for (int j = 0; j < cnt; j++) {
            uint4 q0 = bb[j * 4 + 0];
            uint4 q1 = bb[j * 4 + 1];
            uint4 q2 = bb[j * 4 + 2];
            uint4 q3 = bb[j * 4 + 3];
            UH c;
            float s0 = bias, s1 = 0.f, s2 = 0.f, s3 = 0.f;
            c.u = q0.x; s0 = __builtin_amdgcn_fdot2(c.h, wh[ 0], s0, false);
            c.u = q0.y; s1 = __builtin_amdgcn_fdot2(c.h, wh[ 1], s1, false);
            c.u = q0.z; s2 = __builtin_amdgcn_fdot2(c.h, wh[ 2], s2, false);
            c.u = q0.w; s3 = __builtin_amdgcn_fdot2(c.h, wh[ 3], s3, false);
            c.u = q1.x; s0 = __builtin_amdgcn_fdot2(c.h, wh[ 4], s0, false);
            c.u = q1.y; s1 = __builtin_amdgcn_fdot2(c.h, wh[ 5], s1, false);
            c.u = q1.z; s2 = __builtin_amdgcn_fdot2(c.h, wh[ 6], s2, false);
            c.u = q1.w; s3 = __builtin_amdgcn_fdot2(c.h, wh[ 7], s3, false);
            c.u = q2.x; s0 = __builtin_amdgcn_fdot2(c.h, wh[ 8], s0, false);
            c.u = q2.y; s1 = __builtin_amdgcn_fdot2(c.h, wh[ 9], s1, false);
            c.u = q2.z; s2 = __builtin_amdgcn_fdot2(c.h, wh[10], s2, false);
            c.u = q2.w; s3 = __builtin_amdgcn_fdot2(c.h, wh[11], s3, false);
            c.u = q3.x; s0 = __builtin_amdgcn_fdot2(c.h, wh[12], s0, false);
            c.u = q3.y; s1 = __builtin_amdgcn_fdot2(c.h, wh[13], s1, false);
            c.u = q3.z; s2 = __builtin_amdgcn_fdot2(c.h, wh[14], s2, false);
            c.u = q3.w; s3 = __builtin_amdgcn_fdot2(c.h, wh[15], s3, false);
            acc += fmaxf((s0 + s1) + (s2 + s3), 0.f);
        }
    }
    ntf[(size_t)n * ADP + lane] = acc / fmaxf((float)d, 1.f);
}

// ---------------- K4: node_feat = relu(x @ W_down^T + b_down) ----------------
// Persistent blocks (512 = 2/CU by LDS): stage W once, loop node groups.
__global__ __launch_bounds__(256) void k_down(const float* __restrict__ x,
                                              const float* __restrict__ Wd,
                                              const float* __restrict__ bd,
                                              float* __restrict__ nfeat) {
    __shared__ float lds[IN_CH * 65];   // 66.6KB
    for (int idx = threadIdx.x; idx < IN_CH * ADP; idx += 256) {
        int c = idx >> 8;
        int k = idx & 255;
        lds[k * 65 + c] = Wd[idx];
    }
    __syncthreads();
    int wv = threadIdx.x >> 6;
    int lane = threadIdx.x & 63;
    float b = bd[lane];
    for (int g = blockIdx.x * 4 + wv; g < N_NODES / 8; g += gridDim.x * 4) {
        int n0 = g * 8;
        const float4* r0 = (const float4*)(x + (size_t)(n0 + 0) * IN_CH);
        const float4* r1 = (const float4*)(x + (size_t)(n0 + 1) * IN_CH);
        const float4* r2 = (const float4*)(x + (size_t)(n0 + 2) * IN_CH);
        const float4* r3 = (const float4*)(x + (size_t)(n0 + 3) * IN_CH);
        const float4* r4 = (const float4*)(x + (size_t)(n0 + 4) * IN_CH);
        const float4* r5 = (const float4*)(x + (size_t)(n0 + 5) * IN_CH);
        const float4* r6 = (const float4*)(x + (size_t)(n0 + 6) * IN_CH);
        const float4* r7 = (const float4*)(x + (size_t)(n0 + 7) * IN_CH);
        float a0 = b, a1 = b, a2 = b, a3 = b, a4 = b, a5 = b, a6 = b, a7 = b;
        #pragma unroll 2
        for (int k4 = 0; k4 < IN_CH / 4; k4++) {
            float4 v0 = r0[k4], v1 = r1[k4], v2 = r2[k4], v3 = r3[k4];
            float4 v4 = r4[k4], v5 = r5[k4], v6 = r6[k4], v7 = r7[k4];
            const float* p0 = (const float*)&v0;
            const float* p1 = (const float*)&v1;
            const float* p2 = (const float*)&v2;
            const float* p3 = (const float*)&v3;
            const float* p4 = (const float*)&v4;
            const float* p5 = (const float*)&v5;
            const float* p6 = (const float*)&v6;
            const float* p7 = (const float*)&v7;
            #pragma unroll
            for (int j = 0; j < 4; j++) {
                float wt = lds[(4 * k4 + j) * 65 + lane];
                a0 += p0[j] * wt; a1 += p1[j] * wt; a2 += p2[j] * wt; a3 += p3[j] * wt;
                a4 += p4[j] * wt; a5 += p5[j] * wt; a6 += p6[j] * wt; a7 += p7[j] * wt;
            }
        }
        nfeat[(size_t)(n0 + 0) * ADP + lane] = fmaxf(a0, 0.f);
        nfeat[(size_t)(n0 + 1) * ADP + lane] = fmaxf(a1, 0.f);
        nfeat[(size_t)(n0 + 2) * ADP + lane] = fmaxf(a2, 0.f);
        nfeat[(size_t)(n0 + 3) * ADP + lane] = fmaxf(a3, 0.f);
        nfeat[(size_t)(n0 + 4) * ADP + lane] = fmaxf(a4, 0.f);
        nfeat[(size_t)(n0 + 5) * ADP + lane] = fmaxf(a5, 0.f);
        nfeat[(size_t)(n0 + 6) * ADP + lane] = fmaxf(a6, 0.f);
        nfeat[(size_t)(n0 + 7) * ADP + lane] = fmaxf(a7, 0.f);
    }
}

// ---------------- K5: fused = relu(W_fusion @ [nf | ntf] + b) ----------------
__global__ __launch_bounds__(256) void k_fuse(const float* __restrict__ nfeat,
                                              const float* __restrict__ ntf,
                                              const float* __restrict__ Wf,
                                              const float* __restrict__ bf,
                                              float* __restrict__ fused) {
    __shared__ float lds[2 * ADP * 65];  // 33.3KB
    for (int idx = threadIdx.x; idx < 2 * ADP * ADP; idx += 256) {
        int c = idx >> 7;
        int k = idx & 127;
        lds[k * 65 + c] = Wf[idx];
    }
    __syncthreads();
    int wv = threadIdx.x >> 6;
    int lane = threadIdx.x & 63;
    float b = bf[lane];
    for (int g = blockIdx.x * 4 + wv; g < N_NODES / 8; g += gridDim.x * 4) {
        int n0 = g * 8;
        float a0 = b, a1 = b, a2 = b, a3 = b, a4 = b, a5 = b, a6 = b, a7 = b;
        #pragma unroll
        for (int half = 0; half < 2; half++) {
            const float* srcbase = half ? ntf : nfeat;
            const float4* r0 = (const float4*)(srcbase + (size_t)(n0 + 0) * ADP);
            const float4* r1 = (const float4*)(srcbase + (size_t)(n0 + 1) * ADP);
            const float4* r2 = (const float4*)(srcbase + (size_t)(n0 + 2) * ADP);
            const float4* r3 = (const float4*)(srcbase + (size_t)(n0 + 3) * ADP);
            const float4* r4 = (const float4*)(srcbase + (size_t)(n0 + 4) * ADP);
            const float4* r5 = (const float4*)(srcbase + (size_t)(n0 + 5) * ADP);
            const float4* r6 = (const float4*)(srcbase + (size_t)(n0 + 6) * ADP);
            const float4* r7 = (const float4*)(srcbase + (size_t)(n0 + 7) * ADP);
            #pragma unroll 2
            for (int k4 = 0; k4 < ADP / 4; k4++) {
                float4 v0 = r0[k4], v1 = r1[k4], v2 = r2[k4], v3 = r3[k4];
                float4 v4 = r4[k4], v5 = r5[k4], v6 = r6[k4], v7 = r7[k4];
                const float* p0 = (const float*)&v0;
                const float* p1 = (const float*)&v1;
                const float* p2 = (const float*)&v2;
                const float* p3 = (const float*)&v3;
                const float* p4 = (const float*)&v4;
                const float* p5 = (const float*)&v5;
                const float* p6 = (const float*)&v6;
                const float* p7 = (const float*)&v7;
                #pragma unroll
                for (int j = 0; j < 4; j++) {
                    float wt = lds[(half * ADP + 4 * k4 + j) * 65 + lane];
                    a0 += p0[j] * wt; a1 += p1[j] * wt; a2 += p2[j] * wt; a3 += p3[j] * wt;
                    a4 += p4[j] * wt; a5 += p5[j] * wt; a6 += p6[j] * wt; a7 += p7[j] * wt;
                }
            }
        }
        fused[(size_t)(n0 + 0) * ADP + lane] = fmaxf(a0, 0.f);
        fused[(size_t)(n0 + 1) * ADP + lane] = fmaxf(a1, 0.f);
        fused[(size_t)(n0 + 2) * ADP + lane] = fmaxf(a2, 0.f);
        fused[(size_t)(n0 + 3) * ADP + lane] = fmaxf(a3, 0.f);
        fused[(size_t)(n0 + 4) * ADP + lane] = fmaxf(a4, 0.f);
        fused[(size_t)(n0 + 5) * ADP + lane] = fmaxf(a5, 0.f);
        fused[(size_t)(n0 + 6) * ADP + lane] = fmaxf(a6, 0.f);
        fused[(size_t)(n0 + 7) * ADP + lane] = fmaxf(a7, 0.f);
    }
}

// ---------------- K6: out = x + fused @ W_up^T + b_up ------------------------
__global__ __launch_bounds__(256) void k_up(const float* __restrict__ fused,
                                            const float* __restrict__ x,
                                            const float* __restrict__ Wu,
                                            const float* __restrict__ bu,
                                            float* __restrict__ out) {
    int t = threadIdx.x;
    float w[ADP];
    {
        const float4* w4 = (const float4*)(Wu + (size_t)t * ADP);
        #pragma unroll
        for (int k4 = 0; k4 < ADP / 4; k4++) {
            float4 v = w4[k4];
            w[4*k4+0] = v.x; w[4*k4+1] = v.y; w[4*k4+2] = v.z; w[4*k4+3] = v.w;
        }
    }
    float b = bu[t];
    for (int n = blockIdx.x * 2; n < N_NODES; n += gridDim.x * 2) {
        const float4* f0 = (const float4*)(fused + (size_t)n * ADP);
        const float4* f1 = (const float4*)(fused + (size_t)(n + 1) * ADP);
        float acc0 = b, acc1 = b;
        #pragma unroll
        for (int k4 = 0; k4 < ADP / 4; k4++) {
            float4 v0 = f0[k4], v1 = f1[k4];
            acc0 += v0.x*w[4*k4+0] + v0.y*w[4*k4+1] + v0.z*w[4*k4+2] + v0.w*w[4*k4+3];
            acc1 += v1.x*w[4*k4+0] + v1.y*w[4*k4+1] + v1.z*w[4*k4+2] + v1.w*w[4*k4+3];
        }
        size_t o0 = (size_t)n * IN_CH + t;
        size_t o1 = (size_t)(n + 1) * IN_CH + t;
        out[o0] = x[o0] + acc0;
        out[o1] = x[o1] + acc1;
    }
}

extern "C" void kernel_launch(void* const* d_in, const int* in_sizes, int n_in,
                              void* d_out, int out_size, void* d_ws, size_t ws_size,
                              hipStream_t stream) {
    const float* x   = (const float*)d_in[0];
    const int*   ei  = (const int*)d_in[1];     // [2, E]; row 0 = src
    const float* ea  = (const float*)d_in[2];
    const float* Wd  = (const float*)d_in[3];
    const float* bd  = (const float*)d_in[4];
    const float* Wt  = (const float*)d_in[5];
    const float* bt  = (const float*)d_in[6];
    const float* Wf  = (const float*)d_in[7];
    const float* bf  = (const float*)d_in[8];
    const float* Wu  = (const float*)d_in[9];
    const float* bu  = (const float*)d_in[10];
    float* out = (float*)d_out;

    int* deg    = (int*)d_ws;                       // [N]
    int* offs   = deg + N_NODES;                    // [N]
    int* cursor = offs + N_NODES;                   // [N]
    int* bsum   = cursor + N_NODES;                 // [256]
    int* bpre   = bsum + 256;                       // [256]
    int* elist  = bpre + 256;                       // [E]
    float* ntf   = (float*)(elist + N_EDGES);       // [N*64]
    float* nfeat = ntf + (size_t)N_NODES * ADP;     // [N*64]
    float* fused = nfeat + (size_t)N_NODES * ADP;   // [N*64]

    (void)hipMemsetAsync(deg, 0, N_NODES * sizeof(int), stream);

    k_hist      <<< 6250, 256, 0, stream>>>(ei, deg);
    k_bsum      <<<NB_SCAN, 256, 0, stream>>>(deg, bsum);
    k_bscan     <<<    1, 256, 0, stream>>>(bsum, bpre);
    k_offs      <<<NB_SCAN, 256, 0, stream>>>(deg, bpre, offs, cursor);
    k_scatter   <<< 6250, 256, 0, stream>>>(ei, cursor, elist);
    k_gatherproj<<<12500, 256, 0, stream>>>(ea, offs, deg, elist, Wt, bt, ntf);
    k_down      <<<  512, 256, 0, stream>>>(x, Wd, bd, nfeat);
    k_fuse      <<< 1024, 256, 0, stream>>>(nfeat, ntf, Wf, bf, fused);
    k_up        <<< 4096, 256, 0, stream>>>(fused, x, Wu, bu, out);
}